// Round 10
// baseline (349.850 us; speedup 1.0000x reference)
//
#include <hip/hip_runtime.h>
#include <cstdint>
#include <cstddef>

typedef short s8v __attribute__((ext_vector_type(8)));
typedef short s4v __attribute__((ext_vector_type(4)));
typedef float f4v __attribute__((ext_vector_type(4)));

static __device__ __forceinline__ float b2f(short s){
  return __uint_as_float(((uint32_t)(uint16_t)s) << 16);
}
static __device__ __forceinline__ short f2bf(float f){
  uint32_t u = __float_as_uint(f);
  u = (u + 0x7fffu + ((u >> 16) & 1u)) >> 16;
  return (short)(uint16_t)u;
}

// ---- graph prep ----
__global__ void k_deg(const int* __restrict__ tgt, int* __restrict__ deg, int nE){
  int e = blockIdx.x*blockDim.x + threadIdx.x;
  if(e < nE) atomicAdd(&deg[tgt[e]], 1);
}
__global__ void k_dinv(const int* __restrict__ deg, float* __restrict__ dinv, int nN){
  int i = blockIdx.x*blockDim.x + threadIdx.x;
  if(i < nN) dinv[i] = rsqrtf((float)deg[i] + 1.0f); // +1 self-loop
}
// WT[n][k] = bf16(W[k][n])
__global__ void k_transpose_cvt(const float* __restrict__ W, short* __restrict__ WT, int K, int N){
  int g = blockIdx.x*blockDim.x + threadIdx.x;
  if(g >= K*N) return;
  int n = g / K, k = g % K;
  WT[(size_t)n*K + k] = f2bf(W[(size_t)k*N + n]);
}
// graph boundaries in sorted batch
__global__ void k_bounds(const int* __restrict__ batch, int* __restrict__ gstart,
                         int nN, int nG){
  int g = threadIdx.x;
  if(g > nG) return;
  int lo = 0, hi = nN;
  while(lo < hi){
    int mid = (lo + hi) >> 1;
    if(batch[mid] < g) lo = mid + 1; else hi = mid;
  }
  gstart[g] = lo;
}

// ---- CSR build ----
#define SCAN_BS 256
__global__ void k_scan1(const int* __restrict__ deg, int* __restrict__ rowptr,
                        int* __restrict__ blocksum, int nN){
  __shared__ int tmp[SCAN_BS];
  const int t = threadIdx.x;
  const int i = blockIdx.x*SCAN_BS + t;
  int v = (i < nN) ? deg[i] : 0;
  tmp[t] = v; __syncthreads();
  #pragma unroll
  for(int off=1; off<SCAN_BS; off<<=1){
    int x = (t >= off) ? tmp[t-off] : 0;
    __syncthreads();
    tmp[t] += x;
    __syncthreads();
  }
  if(i < nN) rowptr[i] = tmp[t] - v;
  if(t == SCAN_BS-1) blocksum[blockIdx.x] = tmp[t];
}
__global__ void k_scan2(int* __restrict__ blocksum, int nb){
  __shared__ int tmp[1024];
  const int t = threadIdx.x;
  int v = (t < nb) ? blocksum[t] : 0;
  tmp[t] = v; __syncthreads();
  #pragma unroll
  for(int off=1; off<1024; off<<=1){
    int x = (t >= off) ? tmp[t-off] : 0;
    __syncthreads();
    tmp[t] += x;
    __syncthreads();
  }
  if(t < nb) blocksum[t] = tmp[t] - v;
}
__global__ void k_scan3(int* __restrict__ rowptr, const int* __restrict__ blocksum,
                        int nN, int nE){
  const int i = blockIdx.x*SCAN_BS + threadIdx.x;
  if(i < nN) rowptr[i] += blocksum[blockIdx.x];
  if(i == 0) rowptr[nN] = nE;
}
__global__ void k_fill(const int* __restrict__ src, const int* __restrict__ tgt,
                       const int* __restrict__ rowptr, int* __restrict__ cursor,
                       int* __restrict__ csr_src, float* __restrict__ csr_w,
                       const float* __restrict__ dinv, int nE){
  int e = blockIdx.x*blockDim.x + threadIdx.x;
  if(e >= nE) return;
  int t = tgt[e];
  int s = src[e];
  int pos = rowptr[t] + atomicAdd(&cursor[t], 1);
  csr_src[pos] = s;
  csr_w[pos] = dinv[s] * dinv[t];
}

// ---- barrier-free wave-independent GEMM ----
// C[m][n] = sum_k A[m][k]*Bt[n][k]. Each WAVE independently owns a
// 32-row x 128-col output tile. No LDS, no barriers, no inter-wave sync:
// A fragments global->reg (used once, converted in-reg for f32), W fragments
// straight from L2 (W is only 384 KB -> L2-resident; per-wave reads trade
// redundancy for zero synchronization). Depth-2 named-register prefetch;
// 12 independent waves/CU keep the memory pipe continuously fed.
template<bool AF32>
__global__ __launch_bounds__(256) void gemm_wave(const void* __restrict__ Ap,
    const short* __restrict__ Bt, short* __restrict__ C, int M, int N, int K)
{
  const int tid  = threadIdx.x;
  const int lane = tid & 63;
  const int wv   = tid >> 6;
  const int lr   = lane & 15;
  const int hi   = lane >> 4;
  const int row_base = blockIdx.x*128 + wv*32;   // this wave's 32 rows
  const int col0     = blockIdx.y*128;           // this block's 128 cols
  const int nkc = K / 32;

  f4v acc[2][8];
  #pragma unroll
  for(int s=0;s<2;s++)
    #pragma unroll
    for(int nf=0;nf<8;nf++){ acc[s][nf][0]=0.f; acc[s][nf][1]=0.f; acc[s][nf][2]=0.f; acc[s][nf][3]=0.f; }

  // per-lane A row pointers (clamped)
  int r0 = row_base + lr;       if(r0 >= M) r0 = M-1;
  int r1 = row_base + 16 + lr;  if(r1 >= M) r1 = M-1;
  const char* A0p = (const char*)Ap + (size_t)r0 * K * (AF32?4:2);
  const char* A1p = (const char*)Ap + (size_t)r1 * K * (AF32?4:2);
  // per-lane B base: col = col0 + lr (+ nf*16), k = hi*8
  const short* Bl = Bt + (size_t)(col0 + lr)*K + hi*8;

  auto LDW = [&](int kc, s8v* w){
    #pragma unroll
    for(int nf=0;nf<8;nf++)
      w[nf] = *(const s8v*)(Bl + (size_t)nf*16*K + kc*32);
  };
  auto LDA = [&](int kc, s8v* a){
    if constexpr(AF32){
      const int off = (kc*32 + hi*8)*4;
      f4v l0 = *(const f4v*)(A0p + off);
      f4v h0 = *(const f4v*)(A0p + off + 16);
      f4v l1 = *(const f4v*)(A1p + off);
      f4v h1 = *(const f4v*)(A1p + off + 16);
      s8v v0, v1;
      #pragma unroll
      for(int q=0;q<4;q++){
        v0[q] = f2bf(l0[q]); v0[4+q] = f2bf(h0[q]);
        v1[q] = f2bf(l1[q]); v1[4+q] = f2bf(h1[q]);
      }
      a[0] = v0; a[1] = v1;
    } else {
      const int off = (kc*32 + hi*8)*2;
      a[0] = *(const s8v*)(A0p + off);
      a[1] = *(const s8v*)(A1p + off);
    }
  };
  auto FMA = [&](s8v* a, s8v* w){
    #pragma unroll
    for(int nf=0;nf<8;nf++){
      acc[0][nf] = __builtin_amdgcn_mfma_f32_16x16x32_bf16(a[0], w[nf], acc[0][nf], 0, 0, 0);
      acc[1][nf] = __builtin_amdgcn_mfma_f32_16x16x32_bf16(a[1], w[nf], acc[1][nf], 0, 0, 0);
    }
  };

  s8v W0[8], W1[8], Af0[2], Af1[2];
  LDW(0, W0); LDA(0, Af0);
  LDW(1, W1); LDA(1, Af1);
  for(int kc=0; kc<nkc; kc+=2){
    FMA(Af0, W0);
    if(kc+2 < nkc){ LDW(kc+2, W0); LDA(kc+2, Af0); }
    FMA(Af1, W1);
    if(kc+3 < nkc){ LDW(kc+3, W1); LDA(kc+3, Af1); }
  }

  // epilogue: row = row_base + s*16 + hi*4 + j, col = col0 + nf*16 + lr
  #pragma unroll
  for(int s=0;s<2;s++){
    #pragma unroll
    for(int j=0;j<4;j++){
      const int row = row_base + s*16 + hi*4 + j;
      if(row >= M) continue;
      #pragma unroll
      for(int nf=0;nf<8;nf++){
        const int col = col0 + nf*16 + lr;
        C[(size_t)row*N + col] = f2bf(acc[s][nf][j]);
      }
    }
  }
}

// ---- fused aggregation: one wave per node, coalesced idx/weight prefetch + 8-deep gather ----
__global__ __launch_bounds__(256) void k_aggregate(
    const short* __restrict__ h, const float* __restrict__ dinv,
    const int* __restrict__ rowptr, const int* __restrict__ csr_src,
    const float* __restrict__ csr_w, const float* __restrict__ bias,
    short* __restrict__ hout, int nN)
{
  const int wave = threadIdx.x >> 6;
  const int lane = threadIdx.x & 63;
  const int node = blockIdx.x*4 + wave;
  if(node >= nN) return;
  const float di = dinv[node];
  const int beg = rowptr[node];
  const int deg = rowptr[node+1] - beg;

  s4v hv = *(const s4v*)&h[(size_t)node*256 + lane*4];
  const float d2 = di*di;
  f4v acc;
  #pragma unroll
  for(int j=0;j<4;j++) acc[j] = d2 * b2f(hv[j]);

  for(int base=0; base<deg; base+=64){
    const int cnt = min(deg - base, 64);
    int   myi = (lane < cnt) ? csr_src[beg + base + lane] : 0;
    float myw = (lane < cnt) ? csr_w[beg + base + lane] : 0.f;

    for(int p0=0; p0<cnt; p0+=8){
      s4v v[8]; float w[8]; int s[8];
      #pragma unroll
      for(int j=0;j<8;j++){
        int pp = p0 + j;
        int sl = (pp < cnt) ? pp : 0;
        s[j] = __shfl(myi, sl);
        w[j] = (pp < cnt) ? __shfl(myw, sl) : 0.f;
      }
      #pragma unroll
      for(int j=0;j<8;j++)
        v[j] = *(const s4v*)&h[(size_t)s[j]*256 + lane*4];
      #pragma unroll
      for(int j=0;j<8;j++){
        #pragma unroll
        for(int q=0;q<4;q++) acc[q] += w[j] * b2f(v[j][q]);
      }
    }
  }

  f4v bv = *(const f4v*)&bias[lane*4];
  s4v ov;
  #pragma unroll
  for(int j=0;j<4;j++) ov[j] = f2bf(fmaxf(acc[j]+bv[j], 0.f));
  *(s4v*)&hout[(size_t)node*256 + lane*4] = ov;
}

// ---- mean-pool over sorted batch ----
#define POOL_SPLIT 8
__global__ __launch_bounds__(256) void k_pool(const short* __restrict__ h,
    const int* __restrict__ gstart, float* __restrict__ pool, int nG){
  const int g = blockIdx.x;
  const int sl = blockIdx.y;
  const int c = threadIdx.x;
  const int b = gstart[g], e = gstart[g+1];
  const int len = e - b;
  const int r0 = b + (int)((long long)len * sl / POOL_SPLIT);
  const int r1 = b + (int)((long long)len * (sl+1) / POOL_SPLIT);
  float acc = 0.f;
  for(int r=r0; r<r1; r++) acc += b2f(h[(size_t)r*256 + c]);
  if(r1 > r0) atomicAdd(&pool[(size_t)g*256 + c], acc);
}

__global__ void k_final(const float* __restrict__ pool, const int* __restrict__ gstart,
                        const float* __restrict__ Wp, const float* __restrict__ bp,
                        float* __restrict__ out, int HID_, int OUT_){
  __shared__ float mean[256];
  int g = blockIdx.x, j = threadIdx.x;
  float c = fmaxf((float)(gstart[g+1] - gstart[g]), 1.0f);
  for(int k=j; k<HID_; k+=blockDim.x) mean[k] = pool[(size_t)g*HID_ + k] / c;
  __syncthreads();
  float acc = bp[j];
  for(int k=0;k<HID_;k++) acc = fmaf(mean[k], Wp[(size_t)k*OUT_ + j], acc);
  out[(size_t)g*OUT_ + j] = acc;
}

extern "C" void kernel_launch(void* const* d_in, const int* in_sizes, int n_in,
                              void* d_out, int out_size, void* d_ws, size_t ws_size,
                              hipStream_t stream){
  const float* x   = (const float*)d_in[0];
  const int* ei    = (const int*)d_in[1];
  const int* batch = (const int*)d_in[2];
  const float* W1  = (const float*)d_in[3];
  const float* b1  = (const float*)d_in[4];
  const float* W2  = (const float*)d_in[5];
  const float* b2  = (const float*)d_in[6];
  const float* Wp  = (const float*)d_in[7];
  const float* bp  = (const float*)d_in[8];
  float* out = (float*)d_out;

  const int HID    = in_sizes[4];            // 256
  const int IN_DIM = in_sizes[3] / HID;      // 768
  const int OUT    = in_sizes[8];            // 128
  const int nE     = in_sizes[1] / 2;        // 300000
  const int nN     = in_sizes[2];            // 50000
  const int nG     = out_size / OUT;         // 64

  const int* src = ei;
  const int* tgt = ei + nE;

  char* w = (char*)d_ws;
  size_t off = 0;
  auto alloc = [&](size_t bytes)->char*{
    char* p = w + off; off += (bytes + 511) & ~(size_t)511; return p;
  };
  int*   deg     = (int*)  alloc((size_t)nN*4);
  float* dinv    = (float*)alloc((size_t)nN*4);
  int*   gstart  = (int*)  alloc((size_t)(nG+1)*4);
  float* pool    = (float*)alloc((size_t)nG*HID*4);
  int*   rowptr  = (int*)  alloc((size_t)(nN+1)*4);
  int*   cursor  = (int*)  alloc((size_t)nN*4);
  int*   csr_src = (int*)  alloc((size_t)nE*4);
  float* csr_w   = (float*)alloc((size_t)nE*4);
  int*   blocksum= (int*)  alloc((size_t)1024*4);
  short* W1T     = (short*)alloc((size_t)IN_DIM*HID*2);
  short* W2T     = (short*)alloc((size_t)HID*HID*2);
  short* h1      = (short*)alloc((size_t)(nN+128)*HID*2);
  short* h2      = (short*)alloc((size_t)(nN+128)*HID*2);
  (void)ws_size; (void)n_in;

  hipMemsetAsync(deg,    0, (size_t)nN*4, stream);
  hipMemsetAsync(cursor, 0, (size_t)nN*4, stream);
  hipMemsetAsync(pool,   0, (size_t)nG*HID*4, stream);

  const int nb = (nN + SCAN_BS - 1) / SCAN_BS;
  k_deg <<<(nE+255)/256, 256, 0, stream>>>(tgt, deg, nE);
  k_dinv<<<(nN+255)/256, 256, 0, stream>>>(deg, dinv, nN);
  k_bounds<<<1, ((nG+1+63)/64)*64, 0, stream>>>(batch, gstart, nN, nG);
  k_scan1<<<nb, SCAN_BS, 0, stream>>>(deg, rowptr, blocksum, nN);
  k_scan2<<<1, 1024, 0, stream>>>(blocksum, nb);
  k_scan3<<<nb, SCAN_BS, 0, stream>>>(rowptr, blocksum, nN, nE);
  k_fill <<<(nE+255)/256, 256, 0, stream>>>(src, tgt, rowptr, cursor, csr_src, csr_w, dinv, nE);
  k_transpose_cvt<<<(IN_DIM*HID+255)/256, 256, 0, stream>>>(W1, W1T, IN_DIM, HID);
  k_transpose_cvt<<<(HID*HID+255)/256,   256, 0, stream>>>(W2, W2T, HID, HID);

  dim3 gg((nN+127)/128, HID/128);
  const int nagg = (nN + 3) / 4;
  // layer 1
  gemm_wave<true><<<gg, 256, 0, stream>>>(x, W1T, h2, nN, HID, IN_DIM);
  k_aggregate<<<nagg, 256, 0, stream>>>(h2, dinv, rowptr, csr_src, csr_w, b1, h1, nN);
  // layer 2
  gemm_wave<false><<<gg, 256, 0, stream>>>(h1, W2T, h2, nN, HID, HID);
  k_aggregate<<<nagg, 256, 0, stream>>>(h2, dinv, rowptr, csr_src, csr_w, b2, h1, nN);
  k_pool<<<dim3(nG, POOL_SPLIT), 256, 0, stream>>>(h1, gstart, pool, nG);
  // head
  k_final<<<nG, OUT, 0, stream>>>(pool, gstart, Wp, bp, out, HID, OUT);
}

// Round 11
// 246.291 us; speedup vs baseline: 1.4205x; 1.4205x over previous
//
#include <hip/hip_runtime.h>
#include <cstdint>
#include <cstddef>

typedef short s8v __attribute__((ext_vector_type(8)));
typedef short s4v __attribute__((ext_vector_type(4)));
typedef float f4v __attribute__((ext_vector_type(4)));

static __device__ __forceinline__ float b2f(short s){
  return __uint_as_float(((uint32_t)(uint16_t)s) << 16);
}
static __device__ __forceinline__ short f2bf(float f){
  uint32_t u = __float_as_uint(f);
  u = (u + 0x7fffu + ((u >> 16) & 1u)) >> 16;
  return (short)(uint16_t)u;
}
// async global->LDS, 16B per lane, LDS dest = uniform base + lane*16
static __device__ __forceinline__ void gld_lds16(const void* g, void* l){
  __builtin_amdgcn_global_load_lds((const __attribute__((address_space(1))) void*)g,
                                   (__attribute__((address_space(3))) void*)l, 16, 0, 0);
}

// ---- graph prep (fused) ----
__global__ void k_deg(const int* __restrict__ tgt, int* __restrict__ deg, int nE){
  int e = blockIdx.x*blockDim.x + threadIdx.x;
  if(e < nE) atomicAdd(&deg[tgt[e]], 1);
}

#define SCAN_BS 256
// scan1 + dinv fused
__global__ void k_scan1_dinv(const int* __restrict__ deg, int* __restrict__ rowptr,
                             int* __restrict__ blocksum, float* __restrict__ dinv, int nN){
  __shared__ int tmp[SCAN_BS];
  const int t = threadIdx.x;
  const int i = blockIdx.x*SCAN_BS + t;
  int v = (i < nN) ? deg[i] : 0;
  if(i < nN) dinv[i] = rsqrtf((float)v + 1.0f);   // +1 self-loop
  tmp[t] = v; __syncthreads();
  #pragma unroll
  for(int off=1; off<SCAN_BS; off<<=1){
    int x = (t >= off) ? tmp[t-off] : 0;
    __syncthreads();
    tmp[t] += x;
    __syncthreads();
  }
  if(i < nN) rowptr[i] = tmp[t] - v;
  if(t == SCAN_BS-1) blocksum[blockIdx.x] = tmp[t];
}
// scan2 + graph-bounds binary search fused (single block, 1024 thr)
__global__ void k_scan2_bounds(int* __restrict__ blocksum, int nb,
                               const int* __restrict__ batch, int* __restrict__ gstart,
                               int nN, int nG){
  __shared__ int tmp[1024];
  const int t = threadIdx.x;
  int v = (t < nb) ? blocksum[t] : 0;
  tmp[t] = v; __syncthreads();
  #pragma unroll
  for(int off=1; off<1024; off<<=1){
    int x = (t >= off) ? tmp[t-off] : 0;
    __syncthreads();
    tmp[t] += x;
    __syncthreads();
  }
  if(t < nb) blocksum[t] = tmp[t] - v;
  if(t <= nG){
    int lo = 0, hi = nN;
    while(lo < hi){
      int mid = (lo + hi) >> 1;
      if(batch[mid] < t) lo = mid + 1; else hi = mid;
    }
    gstart[t] = lo;
  }
}
__global__ void k_scan3(int* __restrict__ rowptr, const int* __restrict__ blocksum,
                        int nN, int nE){
  const int i = blockIdx.x*SCAN_BS + threadIdx.x;
  if(i < nN) rowptr[i] += blocksum[blockIdx.x];
  if(i == 0) rowptr[nN] = nE;
}
__global__ void k_fill(const int* __restrict__ src, const int* __restrict__ tgt,
                       const int* __restrict__ rowptr, int* __restrict__ cursor,
                       int* __restrict__ csr_src, float* __restrict__ csr_w,
                       const float* __restrict__ dinv, int nE){
  int e = blockIdx.x*blockDim.x + threadIdx.x;
  if(e >= nE) return;
  int t = tgt[e];
  int s = src[e];
  int pos = rowptr[t] + atomicAdd(&cursor[t], 1);
  csr_src[pos] = s;
  csr_w[pos] = dinv[s] * dinv[t];
}
// both weight transposes in one launch: WT[n][k] = bf16(W[k][n])
__global__ void k_transpose_cvt2(const float* __restrict__ W1, short* __restrict__ W1T,
                                 int K1, const float* __restrict__ W2, short* __restrict__ W2T,
                                 int K2, int N){
  int g = blockIdx.x*blockDim.x + threadIdx.x;
  const int t1 = K1*N;
  if(g < t1){
    int n = g / K1, k = g % K1;
    W1T[(size_t)n*K1 + k] = f2bf(W1[(size_t)k*N + n]);
  } else {
    g -= t1;
    if(g >= K2*N) return;
    int n = g / K2, k = g % K2;
    W2T[(size_t)n*K2 + k] = f2bf(W2[(size_t)k*N + n]);
  }
}

// ---- streaming GEMM, async-staged, counted-vmcnt ring (round-6 best config) ----
// C[m][n] = sum_k A[m][k]*Bt[n][k]. 256 thr (4 waves), tile 128x128, K chunks of 32.
// f32 A: D=1, NBUF=3 (72 KB LDS, 2 blocks/CU) — measured best (r6: 88 us).
// bf16 A: D=2, NBUF=4 (64 KB LDS, 2 blocks/CU).
// Ring safety: writer slot (kc+D)%NBUF vs readers {kc-1,kc}%NBUF — distinct
// for NBUF=D+2 under <=1-iteration wave skew (one barrier per iteration).
template<bool AF32>
__global__ __launch_bounds__(256) void gemm_stream(const void* __restrict__ Ap,
    const short* __restrict__ Bt, short* __restrict__ C, int M, int N, int K)
{
  constexpr int KC  = 32;
  constexpr int ESZ = AF32 ? 4 : 2;
  constexpr int AB  = KC * ESZ;          // A bytes per row: 128 | 64
  constexpr int ACPR = AB / 16;          // 16B chunks per A row: 8 | 4
  constexpr int ARPC = 64 / ACPR;        // rows per gld_lds call: 8 | 16
  constexpr int D    = AF32 ? 1 : 2;     // prefetch depth
  constexpr int NBUF = D + 2;            // 3 | 4
  constexpr int IPC  = 32/ARPC + 2;      // stage instr/wave/chunk: 6 | 4
  __shared__ __align__(16) char As[NBUF][128*AB];  // f32: 3x16KB, bf16: 4x8KB
  __shared__ __align__(16) char Bs[NBUF][128*64];  // 3x8KB | 4x8KB
  const int tid  = threadIdx.x;
  const int lane = tid & 63;
  const int wv   = tid >> 6;
  const int lr   = lane & 15;
  const int hi   = lane >> 4;
  const int blk_row = blockIdx.x * 128;
  const int blk_col = blockIdx.y * 128;
  const int nkc = K / KC;

  f4v acc[2][8];
  #pragma unroll
  for(int s=0;s<2;s++)
    #pragma unroll
    for(int nf=0;nf<8;nf++){ acc[s][nf][0]=0.f; acc[s][nf][1]=0.f; acc[s][nf][2]=0.f; acc[s][nf][3]=0.f; }

  const int a_ch = lane & (ACPR-1);
  const int a_ro = lane / ACPR;
  const int w_ch = lane & 3;
  const int w_ro = lane >> 2;

  auto STAGE = [&](int kc, int buf){
    #pragma unroll
    for(int j=0; j<32/ARPC; j++){
      const int base_row = wv*32 + j*ARPC;
      const int lrow = base_row + a_ro;
      int grow = blk_row + lrow; if(grow >= M) grow = M-1;
      int sch;
      if constexpr(AF32) sch = a_ch ^ (lrow & 7);
      else               sch = a_ch ^ ((lrow>>1) & 3);
      const char* g = (const char*)Ap + ((size_t)grow*K + (size_t)kc*KC)*ESZ + (sch<<4);
      gld_lds16(g, (void*)(As[buf] + base_row*AB));
    }
    #pragma unroll
    for(int j=0; j<2; j++){
      const int base_row = wv*32 + j*16;
      const int lrow = base_row + w_ro;
      const int sch = w_ch ^ ((lrow>>1) & 3);
      const char* g = (const char*)Bt + ((size_t)(blk_col + lrow)*K + (size_t)kc*KC)*2 + (sch<<4);
      gld_lds16(g, (void*)(Bs[buf] + base_row*64));
    }
  };

  #pragma unroll
  for(int p=0; p<D; p++) STAGE(p, p);

  for(int kc=0; kc<nkc; kc++){
    if(kc + D < nkc) STAGE(kc+D, (kc+D) % NBUF);
    const int rem = (nkc-1-kc < D ? nkc-1-kc : D) * IPC;
    if     (rem >= 8) asm volatile("s_waitcnt vmcnt(8)" ::: "memory");
    else if(rem >= 6) asm volatile("s_waitcnt vmcnt(6)" ::: "memory");
    else if(rem >= 4) asm volatile("s_waitcnt vmcnt(4)" ::: "memory");
    else              asm volatile("s_waitcnt vmcnt(0)" ::: "memory");
    __builtin_amdgcn_s_barrier();
    __builtin_amdgcn_sched_barrier(0);

    const int buf = kc % NBUF;
    const char* ab = As[buf];
    const char* bb = Bs[buf];

    s8v a[2];
    #pragma unroll
    for(int s=0;s<2;s++){
      const int row = wv*32 + s*16 + lr;
      if constexpr(AF32){
        const int c0 = (2*hi)   ^ (row & 7);
        const int c1 = (2*hi+1) ^ (row & 7);
        f4v lo  = *(const f4v*)(ab + row*128 + (c0<<4));
        f4v hi4 = *(const f4v*)(ab + row*128 + (c1<<4));
        s8v v;
        #pragma unroll
        for(int q=0;q<4;q++){ v[q] = f2bf(lo[q]); v[4+q] = f2bf(hi4[q]); }
        a[s] = v;
      } else {
        const int c = hi ^ ((row>>1) & 3);
        a[s] = *(const s8v*)(ab + row*64 + (c<<4));
      }
    }

    #pragma unroll
    for(int nf=0;nf<8;nf++){
      const int brow = nf*16 + lr;
      const int c = hi ^ ((brow>>1) & 3);
      s8v bfr = *(const s8v*)(bb + brow*64 + (c<<4));
      acc[0][nf] = __builtin_amdgcn_mfma_f32_16x16x32_bf16(a[0], bfr, acc[0][nf], 0, 0, 0);
      acc[1][nf] = __builtin_amdgcn_mfma_f32_16x16x32_bf16(a[1], bfr, acc[1][nf], 0, 0, 0);
    }
  }

  #pragma unroll
  for(int s=0;s<2;s++){
    #pragma unroll
    for(int j=0;j<4;j++){
      const int row = blk_row + wv*32 + s*16 + hi*4 + j;
      if(row >= M) continue;
      #pragma unroll
      for(int nf=0;nf<8;nf++){
        const int col = blk_col + nf*16 + lr;
        C[(size_t)row*N + col] = f2bf(acc[s][nf][j]);
      }
    }
  }
}

// ---- fused aggregation: one wave per node, coalesced idx/weight prefetch + 8-deep gather ----
__global__ __launch_bounds__(256) void k_aggregate(
    const short* __restrict__ h, const float* __restrict__ dinv,
    const int* __restrict__ rowptr, const int* __restrict__ csr_src,
    const float* __restrict__ csr_w, const float* __restrict__ bias,
    short* __restrict__ hout, int nN)
{
  const int wave = threadIdx.x >> 6;
  const int lane = threadIdx.x & 63;
  const int node = blockIdx.x*4 + wave;
  if(node >= nN) return;
  const float di = dinv[node];
  const int beg = rowptr[node];
  const int deg = rowptr[node+1] - beg;

  s4v hv = *(const s4v*)&h[(size_t)node*256 + lane*4];
  const float d2 = di*di;
  f4v acc;
  #pragma unroll
  for(int j=0;j<4;j++) acc[j] = d2 * b2f(hv[j]);

  for(int base=0; base<deg; base+=64){
    const int cnt = min(deg - base, 64);
    int   myi = (lane < cnt) ? csr_src[beg + base + lane] : 0;
    float myw = (lane < cnt) ? csr_w[beg + base + lane] : 0.f;

    for(int p0=0; p0<cnt; p0+=8){
      s4v v[8]; float w[8]; int s[8];
      #pragma unroll
      for(int j=0;j<8;j++){
        int pp = p0 + j;
        int sl = (pp < cnt) ? pp : 0;
        s[j] = __shfl(myi, sl);
        w[j] = (pp < cnt) ? __shfl(myw, sl) : 0.f;
      }
      #pragma unroll
      for(int j=0;j<8;j++)
        v[j] = *(const s4v*)&h[(size_t)s[j]*256 + lane*4];
      #pragma unroll
      for(int j=0;j<8;j++){
        #pragma unroll
        for(int q=0;q<4;q++) acc[q] += w[j] * b2f(v[j][q]);
      }
    }
  }

  f4v bv = *(const f4v*)&bias[lane*4];
  s4v ov;
  #pragma unroll
  for(int j=0;j<4;j++) ov[j] = f2bf(fmaxf(acc[j]+bv[j], 0.f));
  *(s4v*)&hout[(size_t)node*256 + lane*4] = ov;
}

// ---- mean-pool: per-(graph,slice) partial sums, no atomics, no memset ----
#define POOL_SPLIT 8
__global__ __launch_bounds__(256) void k_pool(const short* __restrict__ h,
    const int* __restrict__ gstart, float* __restrict__ pool, int nG){
  const int g = blockIdx.x;
  const int sl = blockIdx.y;
  const int c = threadIdx.x;
  const int b = gstart[g], e = gstart[g+1];
  const int len = e - b;
  const int r0 = b + (int)((long long)len * sl / POOL_SPLIT);
  const int r1 = b + (int)((long long)len * (sl+1) / POOL_SPLIT);
  float acc = 0.f;
  for(int r=r0; r<r1; r++) acc += b2f(h[(size_t)r*256 + c]);
  pool[((size_t)g*POOL_SPLIT + sl)*256 + c] = acc;   // partial, overwritten every call
}

__global__ void k_final(const float* __restrict__ pool, const int* __restrict__ gstart,
                        const float* __restrict__ Wp, const float* __restrict__ bp,
                        float* __restrict__ out, int HID_, int OUT_){
  __shared__ float mean[256];
  int g = blockIdx.x, j = threadIdx.x;
  float c = fmaxf((float)(gstart[g+1] - gstart[g]), 1.0f);
  for(int k=j; k<HID_; k+=blockDim.x){
    float s = 0.f;
    #pragma unroll
    for(int sl=0; sl<POOL_SPLIT; sl++)
      s += pool[((size_t)g*POOL_SPLIT + sl)*HID_ + k];
    mean[k] = s / c;
  }
  __syncthreads();
  float acc = bp[j];
  for(int k=0;k<HID_;k++) acc = fmaf(mean[k], Wp[(size_t)k*OUT_ + j], acc);
  out[(size_t)g*OUT_ + j] = acc;
}

extern "C" void kernel_launch(void* const* d_in, const int* in_sizes, int n_in,
                              void* d_out, int out_size, void* d_ws, size_t ws_size,
                              hipStream_t stream){
  const float* x   = (const float*)d_in[0];
  const int* ei    = (const int*)d_in[1];
  const int* batch = (const int*)d_in[2];
  const float* W1  = (const float*)d_in[3];
  const float* b1  = (const float*)d_in[4];
  const float* W2  = (const float*)d_in[5];
  const float* b2  = (const float*)d_in[6];
  const float* Wp  = (const float*)d_in[7];
  const float* bp  = (const float*)d_in[8];
  float* out = (float*)d_out;

  const int HID    = in_sizes[4];            // 256
  const int IN_DIM = in_sizes[3] / HID;      // 768
  const int OUT    = in_sizes[8];            // 128
  const int nE     = in_sizes[1] / 2;        // 300000
  const int nN     = in_sizes[2];            // 50000
  const int nG     = out_size / OUT;         // 64

  const int* src = ei;
  const int* tgt = ei + nE;

  char* w = (char*)d_ws;
  size_t off = 0;
  auto alloc = [&](size_t bytes)->char*{
    char* p = w + off; off += (bytes + 511) & ~(size_t)511; return p;
  };
  int*   deg     = (int*)  alloc((size_t)nN*4);      // deg+cursor adjacent: one memset
  int*   cursor  = (int*)  alloc((size_t)nN*4);
  float* dinv    = (float*)alloc((size_t)nN*4);
  int*   gstart  = (int*)  alloc((size_t)(nG+1)*4);
  float* pool    = (float*)alloc((size_t)nG*POOL_SPLIT*HID*4);
  int*   rowptr  = (int*)  alloc((size_t)(nN+1)*4);
  int*   csr_src = (int*)  alloc((size_t)nE*4);
  float* csr_w   = (float*)alloc((size_t)nE*4);
  int*   blocksum= (int*)  alloc((size_t)1024*4);
  short* W1T     = (short*)alloc((size_t)IN_DIM*HID*2);
  short* W2T     = (short*)alloc((size_t)HID*HID*2);
  short* h1      = (short*)alloc((size_t)(nN+128)*HID*2);
  short* h2      = (short*)alloc((size_t)(nN+128)*HID*2);
  (void)ws_size; (void)n_in;

  // single memset covers deg + padding + cursor (adjacent allocations)
  hipMemsetAsync(deg, 0, (size_t)((char*)cursor - (char*)deg) + (size_t)nN*4, stream);

  const int nb = (nN + SCAN_BS - 1) / SCAN_BS;
  k_deg <<<(nE+255)/256, 256, 0, stream>>>(tgt, deg, nE);
  k_scan1_dinv<<<nb, SCAN_BS, 0, stream>>>(deg, rowptr, blocksum, dinv, nN);
  k_scan2_bounds<<<1, 1024, 0, stream>>>(blocksum, nb, batch, gstart, nN, nG);
  k_scan3<<<nb, SCAN_BS, 0, stream>>>(rowptr, blocksum, nN, nE);
  k_fill <<<(nE+255)/256, 256, 0, stream>>>(src, tgt, rowptr, cursor, csr_src, csr_w, dinv, nE);
  k_transpose_cvt2<<<((IN_DIM+HID)*HID+255)/256, 256, 0, stream>>>(W1, W1T, IN_DIM, W2, W2T, HID, HID);

  dim3 gg((nN+127)/128, HID/128);
  const int nagg = (nN + 3) / 4;
  // layer 1
  gemm_stream<true><<<gg, 256, 0, stream>>>(x, W1T, h2, nN, HID, IN_DIM);
  k_aggregate<<<nagg, 256, 0, stream>>>(h2, dinv, rowptr, csr_src, csr_w, b1, h1, nN);
  // layer 2
  gemm_stream<false><<<gg, 256, 0, stream>>>(h1, W2T, h2, nN, HID, HID);
  k_aggregate<<<nagg, 256, 0, stream>>>(h2, dinv, rowptr, csr_src, csr_w, b2, h1, nN);
  k_pool<<<dim3(nG, POOL_SPLIT), 256, 0, stream>>>(h1, gstart, pool, nG);
  // head
  k_final<<<nG, OUT, 0, stream>>>(pool, gstart, Wp, bp, out, HID, OUT);
}